// Round 9
// baseline (187.698 us; speedup 1.0000x reference)
//
#include <hip/hip_runtime.h>
#include <hip/hip_bf16.h>

#define B_  32
#define P_  2048
#define C_  19
#define D_  512
#define H_  4
#define DH_ 128
#define NROW (B_*P_)
#define CHP_ 96          // padded K for out-GEMM (3x32)

typedef float f32x4 __attribute__((ext_vector_type(4)));
typedef short bf16x8 __attribute__((ext_vector_type(8)));
typedef unsigned short ushort4v __attribute__((ext_vector_type(4)));

// native cvt -> compiler emits v_cvt_pk_bf16_f32 for pairs (RNE)
__device__ __forceinline__ unsigned short f2bf(float f) {
  union { __hip_bfloat16 h; unsigned short s; } u;
  u.h = __float2bfloat16(f);
  return u.s;
}

__device__ __forceinline__ bf16x8 ld_cvt8(const float* p) {
  f32x4 v0 = *(const f32x4*)p;
  f32x4 v1 = *(const f32x4*)(p + 4);
  bf16x8 a;
  a[0]=(short)f2bf(v0[0]); a[1]=(short)f2bf(v0[1]);
  a[2]=(short)f2bf(v0[2]); a[3]=(short)f2bf(v0[3]);
  a[4]=(short)f2bf(v1[0]); a[5]=(short)f2bf(v1[1]);
  a[6]=(short)f2bf(v1[2]); a[7]=(short)f2bf(v1[3]);
  return a;
}

// ---- prep1: K/V = ce @ W^T + b  (f32) ------------------------------------
__global__ __launch_bounds__(256) void prep1(
    const float* __restrict__ ce,
    const float* __restrict__ Wk, const float* __restrict__ bk,
    const float* __restrict__ Wv, const float* __restrict__ bv,
    float* __restrict__ Kg, float* __restrict__ Vg)
{
  int g = blockIdx.x * 256 + threadIdx.x;
  if (g >= 2*C_*D_) return;
  int which = (g >= C_*D_) ? 1 : 0;
  int idx = which ? (g - C_*D_) : g;
  int c = idx >> 9;
  int n = idx & (D_-1);
  const float* w = (which ? Wv : Wk) + (size_t)n * D_;
  const float* e = ce + (size_t)c * D_;
  float s = 0.f;
  #pragma unroll 8
  for (int d = 0; d < D_; ++d) s = fmaf(e[d], w[d], s);
  s += (which ? bv : bk)[n];
  if (which) Vg[idx] = s; else Kg[idx] = s;
}

// ---- prep2: PERMUTED channel axis p = 4c + h (c=p>>2, h=p&3) --------------
// Mtf frag-order: value (p, m=ks*32+lhi*8+j) -> Mtf[(p>>4)*8192 + ks*512 + (lhi*16+(p&15))*8 + j]
// Utf frag-order: value (n=m, k=p)          -> Utf[((m>>4)*3+(p>>5))*512 + (((p>>3)&3)*16+(m&15))*8 + (p&7)]
__global__ __launch_bounds__(512) void prep2(
    const float* __restrict__ Wq, const float* __restrict__ bq,
    const float* __restrict__ Wo,
    const float* __restrict__ Kg, const float* __restrict__ Vg,
    unsigned short* __restrict__ Mtf, unsigned short* __restrict__ Utf,
    float* __restrict__ s0g)
{
  int p = blockIdx.x;   // 0..95 (permuted channel slot)
  int m = threadIdx.x;  // 0..511

  const int mt_off = (p>>4)*8192 + (m>>5)*512 + ((((m>>3)&3)<<4) + (p&15))*8 + (m&7);
  const int ut_off = ((m>>4)*3 + (p>>5))*512 + ((((p>>3)&3)<<4) + (m&15))*8 + (p&7);

  int c = p >> 2, h = p & 3;
  if (c >= C_) {                       // p in [76,96): dead slots
    if (p < 80) { Mtf[mt_off] = 0; if (m == 0) s0g[p] = 0.f; }
    Utf[ut_off] = 0;
    return;
  }
  const float rs128 = 0.08838834764831843f;  // 1/sqrt(128)
  const float* Kr = Kg + c*D_ + h*DH_;
  const float* Vr = Vg + c*D_ + h*DH_;

  float macc = 0.f;
  #pragma unroll 4
  for (int dh = 0; dh < DH_; ++dh)
    macc = fmaf(Wq[(size_t)(h*DH_+dh)*D_ + m], Kr[dh], macc);
  Mtf[mt_off] = f2bf(macc * rs128);

  float uacc = 0.f;
  const float* wor = Wo + (size_t)m*D_ + h*DH_;
  #pragma unroll 4
  for (int dh = 0; dh < DH_; ++dh)
    uacc = fmaf(wor[dh], Vr[dh], uacc);
  Utf[ut_off] = f2bf(uacc);

  if (m == 0) {
    float sa = 0.f;
    const float* bqr = bq + h*DH_;
    for (int dh = 0; dh < DH_; ++dh) sa = fmaf(bqr[dh], Kr[dh], sa);
    s0g[p] = sa * rs128;
  }
}

// ---- K1: S = x@M~^T (+s0) -> in-register softmax -> WaG -------------------
// ZERO barriers, zero LDS. Wave = 16 rows; block = 4 independent waves (64 rows).
// Softmax over c for fixed h: h = llo&3 is lane-invariant -> shfl_xor(4,8).
__global__ __launch_bounds__(256) void k1_scores(
    const float* __restrict__ x,
    const unsigned short* __restrict__ Mtf,  // frag-ordered [5][16][64][8]
    const float* __restrict__ s0g,           // [80] permuted
    unsigned short* __restrict__ WaG)        // [NROW][96] bf16
{
  const int t    = threadIdx.x;
  const int wave = t >> 6;
  const int lane = t & 63;
  const int lhi  = lane >> 4;
  const int llo  = lane & 15;
  const int row0 = blockIdx.x * 64 + wave * 16;   // this wave's 16 rows

  // S-GEMM: ks-outer, 5 independent accumulators, x read once
  f32x4 acc0 = (f32x4){0,0,0,0}, acc1 = acc0, acc2 = acc0, acc3 = acc0, acc4 = acc0;
  {
    const float* xr = x + (size_t)(row0 + llo)*D_ + lhi*8;
    #pragma unroll
    for (int ks = 0; ks < 16; ++ks) {
      bf16x8 a = ld_cvt8(xr + ks*32);
      acc0 = __builtin_amdgcn_mfma_f32_16x16x32_bf16(a, *(const bf16x8*)(Mtf + 0*8192 + ks*512 + lane*8), acc0, 0, 0, 0);
      acc1 = __builtin_amdgcn_mfma_f32_16x16x32_bf16(a, *(const bf16x8*)(Mtf + 1*8192 + ks*512 + lane*8), acc1, 0, 0, 0);
      acc2 = __builtin_amdgcn_mfma_f32_16x16x32_bf16(a, *(const bf16x8*)(Mtf + 2*8192 + ks*512 + lane*8), acc2, 0, 0, 0);
      acc3 = __builtin_amdgcn_mfma_f32_16x16x32_bf16(a, *(const bf16x8*)(Mtf + 3*8192 + ks*512 + lane*8), acc3, 0, 0, 0);
      acc4 = __builtin_amdgcn_mfma_f32_16x16x32_bf16(a, *(const bf16x8*)(Mtf + 4*8192 + ks*512 + lane*8), acc4, 0, 0, 0);
    }
  }
  // acc[ct][r] = S[local row lhi*4+r][p = ct*16+llo]
  const bool dead = (llo >= 12);   // ct=4: c = 16+(llo>>2) == 19
  float s0v0 = s0g[llo], s0v1 = s0g[16+llo], s0v2 = s0g[32+llo],
        s0v3 = s0g[48+llo], s0v4 = s0g[64+llo];

  #pragma unroll
  for (int r = 0; r < 4; ++r) {
    float v0 = acc0[r] + s0v0;
    float v1 = acc1[r] + s0v1;
    float v2 = acc2[r] + s0v2;
    float v3 = acc3[r] + s0v3;
    float v4 = dead ? -1e30f : (acc4[r] + s0v4);
    float mx = fmaxf(fmaxf(fmaxf(v0, v1), fmaxf(v2, v3)), v4);
    mx = fmaxf(mx, __shfl_xor(mx, 4, 64));
    mx = fmaxf(mx, __shfl_xor(mx, 8, 64));
    float e0 = __expf(v0 - mx), e1 = __expf(v1 - mx), e2 = __expf(v2 - mx),
          e3 = __expf(v3 - mx), e4 = dead ? 0.f : __expf(v4 - mx);
    float sm = e0 + e1 + e2 + e3 + e4;
    sm += __shfl_xor(sm, 4, 64);
    sm += __shfl_xor(sm, 8, 64);
    float inv = 1.f / sm;
    const size_t rowoff = (size_t)(row0 + lhi*4 + r) * CHP_;
    WaG[rowoff +      llo] = f2bf(e0 * inv);
    WaG[rowoff + 16 + llo] = f2bf(e1 * inv);
    WaG[rowoff + 32 + llo] = f2bf(e2 * inv);
    WaG[rowoff + 48 + llo] = f2bf(e3 * inv);
    WaG[rowoff + 64 + llo] = f2bf(e4 * inv);
  }
  // zero pad cols 80..95 (one ushort4 per lane: 16 rows x 4 chunks)
  *(ushort4v*)(WaG + (size_t)(row0 + lhi*4 + (llo & 3))*CHP_ + 80 + (llo >> 2)*4)
      = (ushort4v){0, 0, 0, 0};
}

// ---- K2: out = Wa@U (+bo) + x, LN -----------------------------------------
// One barrier total. Per-wave LDS transpose with wave-local lgkmcnt fences.
__global__ __launch_bounds__(256) void k2_out(
    const float* __restrict__ x,
    const unsigned short* __restrict__ WaG,  // [NROW][96] bf16
    const unsigned short* __restrict__ Utf,  // frag-ordered [32][3][64][8]
    const float* __restrict__ bo,
    const float* __restrict__ gamma, const float* __restrict__ beta,
    float* __restrict__ out)
{
  __shared__ __attribute__((aligned(16))) float Tr[4][16][68];
  __shared__ float rs_[32][2], rq_[32][2];

  const int t    = threadIdx.x;
  const int wave = t >> 6;
  const int lane = t & 63;
  const int lhi  = lane >> 4;
  const int llo  = lane & 15;
  const int rg   = wave >> 1;
  const int cs   = wave & 1;
  const int row0 = blockIdx.x * 32;

  // out-GEMM (K=96): A = WaG rows (L3-hot), B = Utf coalesced (L2-hot)
  f32x4 oacc[16];
  #pragma unroll
  for (int i = 0; i < 16; ++i) oacc[i] = (f32x4){0.f,0.f,0.f,0.f};
  #pragma unroll
  for (int ks = 0; ks < 3; ++ks) {
    bf16x8 a = *(const bf16x8*)(WaG + (size_t)(row0 + rg*16 + llo)*CHP_ + ks*32 + lhi*8);
    #pragma unroll
    for (int tile = 0; tile < 16; ++tile) {
      int ntile = cs*16 + tile;
      bf16x8 b = *(const bf16x8*)(Utf + (size_t)(ntile*3 + ks)*512 + lane*8);
      oacc[tile] = __builtin_amdgcn_mfma_f32_16x16x32_bf16(a, b, oacc[tile], 0, 0, 0);
    }
  }
  // oacc[tile][r] = attn[m = rg*16+lhi*4+r][n = cs*256 + tile*16 + llo]

  // per-wave transpose (fences, NO barriers) -> lane owns one row, float4 cols
  const int rw = rg*16 + llo;
  const float* xrow = x + (size_t)(row0 + rw)*D_;
  float s = 0.f, q = 0.f;
  #pragma unroll
  for (int c2 = 0; c2 < 4; ++c2) {
    #pragma unroll
    for (int tl = 0; tl < 4; ++tl)
      #pragma unroll
      for (int r = 0; r < 4; ++r)
        Tr[wave][lhi*4 + r][tl*16 + llo] = oacc[c2*4 + tl][r];
    asm volatile("s_waitcnt lgkmcnt(0)" ::: "memory");
    __builtin_amdgcn_sched_barrier(0);
    #pragma unroll
    for (int j = 0; j < 4; ++j) {
      f32x4 v = *(const f32x4*)&Tr[wave][llo][j*16 + lhi*4];
      int n4 = cs*256 + c2*64 + j*16 + lhi*4;
      f32x4 xv = *(const f32x4*)(xrow + n4);
      f32x4 bv = *(const f32x4*)(bo + n4);
      f32x4 val = v + xv + bv;
      s += val[0] + val[1] + val[2] + val[3];
      q = fmaf(val[0], val[0], q); q = fmaf(val[1], val[1], q);
      q = fmaf(val[2], val[2], q); q = fmaf(val[3], val[3], q);
      oacc[c2*4 + j] = val;     // now: row rw, cols n4..n4+3
    }
    asm volatile("s_waitcnt lgkmcnt(0)" ::: "memory");
    __builtin_amdgcn_sched_barrier(0);
  }
  s += __shfl_xor(s, 16, 64);
  s += __shfl_xor(s, 32, 64);
  q += __shfl_xor(q, 16, 64);
  q += __shfl_xor(q, 32, 64);
  if (lhi == 0) { rs_[rw][cs] = s; rq_[rw][cs] = q; }
  __syncthreads();
  float sum = rs_[rw][0] + rs_[rw][1];
  float sq  = rq_[rw][0] + rq_[rw][1];
  float mu  = sum * (1.f/(float)D_);
  float var = sq * (1.f/(float)D_) - mu*mu;
  float rstd = rsqrtf(var + 1e-5f);
  float* orow = out + (size_t)(row0 + rw)*D_;
  #pragma unroll
  for (int c2 = 0; c2 < 4; ++c2) {
    #pragma unroll
    for (int j = 0; j < 4; ++j) {
      int n4 = cs*256 + c2*64 + j*16 + lhi*4;
      f32x4 gv = *(const f32x4*)(gamma + n4);
      f32x4 bt = *(const f32x4*)(beta + n4);
      f32x4 val = oacc[c2*4 + j];
      f32x4 o;
      o[0] = (val[0] - mu) * rstd * gv[0] + bt[0];
      o[1] = (val[1] - mu) * rstd * gv[1] + bt[1];
      o[2] = (val[2] - mu) * rstd * gv[2] + bt[2];
      o[3] = (val[3] - mu) * rstd * gv[3] + bt[3];
      *(f32x4*)(orow + n4) = o;
    }
  }
}

extern "C" void kernel_launch(void* const* d_in, const int* in_sizes, int n_in,
                              void* d_out, int out_size, void* d_ws, size_t ws_size,
                              hipStream_t stream) {
  const float* x     = (const float*)d_in[0];
  const float* ce    = (const float*)d_in[1];
  const float* Wq    = (const float*)d_in[2];
  const float* bq    = (const float*)d_in[3];
  const float* Wk    = (const float*)d_in[4];
  const float* bk    = (const float*)d_in[5];
  const float* Wv    = (const float*)d_in[6];
  const float* bv    = (const float*)d_in[7];
  const float* Wo    = (const float*)d_in[8];
  const float* bo    = (const float*)d_in[9];
  const float* gamma = (const float*)d_in[10];
  const float* beta  = (const float*)d_in[11];
  float* out = (float*)d_out;

  char* ws = (char*)d_ws;
  float* Kg           = (float*)(ws);                   // 38912
  float* Vg           = (float*)(ws + 40960);           // 38912
  unsigned short* Mtf = (unsigned short*)(ws + 81920);  // 80*512*2 = 81920
  unsigned short* Utf = (unsigned short*)(ws + 163840); // 512*96*2 = 98304
  float* s0g          = (float*)(ws + 262144);          // 320
  unsigned short* WaG = (unsigned short*)(ws + 263168); // 65536*96*2 = 12.6MB

  prep1<<<(2*C_*D_)/256, 256, 0, stream>>>(ce, Wk, bk, Wv, bv, Kg, Vg);
  prep2<<<CHP_, 512, 0, stream>>>(Wq, bq, Wo, Kg, Vg, Mtf, Utf, s0g);
  k1_scores<<<NROW/64, 256, 0, stream>>>(x, Mtf, s0g, WaG);
  k2_out<<<NROW/32, 256, 0, stream>>>(x, WaG, Utf, bo, gamma, beta, out);
}

// Round 10
// 139.901 us; speedup vs baseline: 1.3416x; 1.3416x over previous
//
#include <hip/hip_runtime.h>
#include <hip/hip_bf16.h>

#define B_  32
#define P_  2048
#define C_  19
#define D_  512
#define H_  4
#define DH_ 128
#define NROW (B_*P_)
#define CHP_ 96          // padded K for out-GEMM (3x32)

typedef float f32x4 __attribute__((ext_vector_type(4)));
typedef short bf16x8 __attribute__((ext_vector_type(8)));
typedef unsigned short ushort4v __attribute__((ext_vector_type(4)));

__device__ __forceinline__ unsigned short f2bf(float f) {
  union { __hip_bfloat16 h; unsigned short s; } u;
  u.h = __float2bfloat16(f);
  return u.s;
}

__device__ __forceinline__ bf16x8 ld_cvt8(const float* p) {
  f32x4 v0 = *(const f32x4*)p;
  f32x4 v1 = *(const f32x4*)(p + 4);
  bf16x8 a;
  a[0]=(short)f2bf(v0[0]); a[1]=(short)f2bf(v0[1]);
  a[2]=(short)f2bf(v0[2]); a[3]=(short)f2bf(v0[3]);
  a[4]=(short)f2bf(v1[0]); a[5]=(short)f2bf(v1[1]);
  a[6]=(short)f2bf(v1[2]); a[7]=(short)f2bf(v1[3]);
  return a;
}

// ---- prep1: K/V = ce @ W^T + b  (f32) ------------------------------------
__global__ __launch_bounds__(256) void prep1(
    const float* __restrict__ ce,
    const float* __restrict__ Wk, const float* __restrict__ bk,
    const float* __restrict__ Wv, const float* __restrict__ bv,
    float* __restrict__ Kg, float* __restrict__ Vg)
{
  int g = blockIdx.x * 256 + threadIdx.x;
  if (g >= 2*C_*D_) return;
  int which = (g >= C_*D_) ? 1 : 0;
  int idx = which ? (g - C_*D_) : g;
  int c = idx >> 9;
  int n = idx & (D_-1);
  const float* w = (which ? Wv : Wk) + (size_t)n * D_;
  const float* e = ce + (size_t)c * D_;
  float s = 0.f;
  #pragma unroll 8
  for (int d = 0; d < D_; ++d) s = fmaf(e[d], w[d], s);
  s += (which ? bv : bk)[n];
  if (which) Vg[idx] = s; else Kg[idx] = s;
}

// ---- prep2 (r9-verbatim): PERMUTED channel axis p = 4c + h ----------------
__global__ __launch_bounds__(512) void prep2(
    const float* __restrict__ Wq, const float* __restrict__ bq,
    const float* __restrict__ Wo,
    const float* __restrict__ Kg, const float* __restrict__ Vg,
    unsigned short* __restrict__ Mtf, unsigned short* __restrict__ Utf,
    float* __restrict__ s0g)
{
  int p = blockIdx.x;   // 0..95 (permuted channel slot)
  int m = threadIdx.x;  // 0..511

  const int mt_off = (p>>4)*8192 + (m>>5)*512 + ((((m>>3)&3)<<4) + (p&15))*8 + (m&7);
  const int ut_off = ((m>>4)*3 + (p>>5))*512 + ((((p>>3)&3)<<4) + (m&15))*8 + (p&7);

  int c = p >> 2, h = p & 3;
  if (c >= C_) {                       // p in [76,96): dead slots
    if (p < 80) { Mtf[mt_off] = 0; if (m == 0) s0g[p] = 0.f; }
    Utf[ut_off] = 0;
    return;
  }
  const float rs128 = 0.08838834764831843f;  // 1/sqrt(128)
  const float* Kr = Kg + c*D_ + h*DH_;
  const float* Vr = Vg + c*D_ + h*DH_;

  float macc = 0.f;
  #pragma unroll 4
  for (int dh = 0; dh < DH_; ++dh)
    macc = fmaf(Wq[(size_t)(h*DH_+dh)*D_ + m], Kr[dh], macc);
  Mtf[mt_off] = f2bf(macc * rs128);

  float uacc = 0.f;
  const float* wor = Wo + (size_t)m*D_ + h*DH_;
  #pragma unroll 4
  for (int dh = 0; dh < DH_; ++dh)
    uacc = fmaf(wor[dh], Vr[dh], uacc);
  Utf[ut_off] = f2bf(uacc);

  if (m == 0) {
    float sa = 0.f;
    const float* bqr = bq + h*DH_;
    for (int dh = 0; dh < DH_; ++dh) sa = fmaf(bqr[dh], Kr[dh], sa);
    s0g[p] = sa * rs128;
  }
}

// ---- fused64: 64 rows/block, 4 waves; each wave owns 16 rows for scores ---
// phase1+softmax: r9-k1 verbatim (in-register, no barriers), Wa -> LDS.
// phase3/4: two 32-row halves, r9-k2 GEMM + r6 epilogue. 3 barriers total.
__global__ __launch_bounds__(256) void fused64(
    const float* __restrict__ x,
    const unsigned short* __restrict__ Mtf,  // frag-ordered [5][16][64][8]
    const unsigned short* __restrict__ Utf,  // frag-ordered [32][3][64][8]
    const float* __restrict__ s0g,           // [80] permuted
    const float* __restrict__ bo,
    const float* __restrict__ gamma, const float* __restrict__ beta,
    float* __restrict__ out)
{
  __shared__ __attribute__((aligned(16))) unsigned short WaL[64][104]; // cols 76..95 zero
  __shared__ float rs_[64][2], rq_[64][2];

  const int t    = threadIdx.x;
  const int wave = t >> 6;
  const int lane = t & 63;
  const int lhi  = lane >> 4;
  const int llo  = lane & 15;
  const int row0 = blockIdx.x * 64;

  // ---- phase 1: S-GEMM, ks-outer, 5 accs; this wave's 16 rows ----
  {
    const int wrow = wave * 16;     // local row base
    f32x4 acc0 = (f32x4){0,0,0,0}, acc1 = acc0, acc2 = acc0, acc3 = acc0, acc4 = acc0;
    const float* xr = x + (size_t)(row0 + wrow + llo)*D_ + lhi*8;
    #pragma unroll
    for (int ks = 0; ks < 16; ++ks) {
      bf16x8 a = ld_cvt8(xr + ks*32);
      acc0 = __builtin_amdgcn_mfma_f32_16x16x32_bf16(a, *(const bf16x8*)(Mtf + 0*8192 + ks*512 + lane*8), acc0, 0, 0, 0);
      acc1 = __builtin_amdgcn_mfma_f32_16x16x32_bf16(a, *(const bf16x8*)(Mtf + 1*8192 + ks*512 + lane*8), acc1, 0, 0, 0);
      acc2 = __builtin_amdgcn_mfma_f32_16x16x32_bf16(a, *(const bf16x8*)(Mtf + 2*8192 + ks*512 + lane*8), acc2, 0, 0, 0);
      acc3 = __builtin_amdgcn_mfma_f32_16x16x32_bf16(a, *(const bf16x8*)(Mtf + 3*8192 + ks*512 + lane*8), acc3, 0, 0, 0);
      acc4 = __builtin_amdgcn_mfma_f32_16x16x32_bf16(a, *(const bf16x8*)(Mtf + 4*8192 + ks*512 + lane*8), acc4, 0, 0, 0);
    }
    // in-register softmax over p (h = llo&3 lane-invariant under xor 4,8)
    const bool dead = (llo >= 12);   // slot p=64+llo: c=16+(llo>>2) == 19
    float s0v0 = s0g[llo], s0v1 = s0g[16+llo], s0v2 = s0g[32+llo],
          s0v3 = s0g[48+llo], s0v4 = s0g[64+llo];
    #pragma unroll
    for (int r = 0; r < 4; ++r) {
      float v0 = acc0[r] + s0v0;
      float v1 = acc1[r] + s0v1;
      float v2 = acc2[r] + s0v2;
      float v3 = acc3[r] + s0v3;
      float v4 = dead ? -1e30f : (acc4[r] + s0v4);
      float mx = fmaxf(fmaxf(fmaxf(v0, v1), fmaxf(v2, v3)), v4);
      mx = fmaxf(mx, __shfl_xor(mx, 4, 64));
      mx = fmaxf(mx, __shfl_xor(mx, 8, 64));
      float e0 = __expf(v0 - mx), e1 = __expf(v1 - mx), e2 = __expf(v2 - mx),
            e3 = __expf(v3 - mx), e4 = dead ? 0.f : __expf(v4 - mx);
      float sm = e0 + e1 + e2 + e3 + e4;
      sm += __shfl_xor(sm, 4, 64);
      sm += __shfl_xor(sm, 8, 64);
      float inv = 1.f / sm;
      int lr = wrow + lhi*4 + r;
      WaL[lr][     llo] = f2bf(e0 * inv);
      WaL[lr][16 + llo] = f2bf(e1 * inv);
      WaL[lr][32 + llo] = f2bf(e2 * inv);
      WaL[lr][48 + llo] = f2bf(e3 * inv);
      WaL[lr][64 + llo] = f2bf(e4 * inv);
    }
    // zero pad cols 80..95 for this wave's rows (plus 76..79 slot already
    // written by e4 path? no: cols 76..79 are p=76..79 dead -> e4*inv with
    // acc4 dead lanes llo 12..15 gives 0; cols 80..95 zeroed here)
    *(ushort4v*)&WaL[wrow + lhi*4 + (llo & 3)][80 + (llo >> 2)*4] = (ushort4v){0,0,0,0};
  }
  __syncthreads();   // BAR1: WaL ready

  // ---- phases 3+4, per 32-row half ----
  const int rg = wave >> 1;
  const int cs = wave & 1;
  #pragma unroll
  for (int ha = 0; ha < 2; ++ha) {
    const int hrow = ha * 32;              // local row base of this half
    f32x4 oacc[16];
    #pragma unroll
    for (int i = 0; i < 16; ++i) oacc[i] = (f32x4){0.f,0.f,0.f,0.f};
    #pragma unroll
    for (int ks = 0; ks < 3; ++ks) {
      bf16x8 a = *(const bf16x8*)&WaL[hrow + rg*16 + llo][ks*32 + lhi*8];
      #pragma unroll
      for (int tile = 0; tile < 16; ++tile) {
        int ntile = cs*16 + tile;
        bf16x8 b = *(const bf16x8*)(Utf + (size_t)(ntile*3 + ks)*512 + lane*8);
        oacc[tile] = __builtin_amdgcn_mfma_f32_16x16x32_bf16(a, b, oacc[tile], 0, 0, 0);
      }
    }
    // oacc[tile][r] = attn[local m = hrow+rg*16+lhi*4+r][n = cs*256+tile*16+llo]

    // epilogue (r6-verbatim): +bo, +x residual, LN stats, store
    float s[4] = {0,0,0,0}, q[4] = {0,0,0,0};
    #pragma unroll
    for (int tile = 0; tile < 16; ++tile) {
      int n = cs*256 + tile*16 + llo;
      float bov = bo[n];
      #pragma unroll
      for (int r = 0; r < 4; ++r) {
        int m = hrow + rg*16 + lhi*4 + r;
        float val = oacc[tile][r] + bov + x[(size_t)(row0 + m)*D_ + n];
        oacc[tile][r] = val;
        s[r] += val;
        q[r] = fmaf(val, val, q[r]);
      }
    }
    #pragma unroll
    for (int r = 0; r < 4; ++r) {
      #pragma unroll
      for (int off = 1; off < 16; off <<= 1) {
        s[r] += __shfl_xor(s[r], off, 64);
        q[r] += __shfl_xor(q[r], off, 64);
      }
    }
    if (llo == 0) {
      #pragma unroll
      for (int r = 0; r < 4; ++r) {
        rs_[hrow + rg*16 + lhi*4 + r][cs] = s[r];
        rq_[hrow + rg*16 + lhi*4 + r][cs] = q[r];
      }
    }
    __syncthreads();   // BAR2 / BAR3: stats for this half ready (disjoint slots)
    float mu_r[4], rstd_r[4];
    #pragma unroll
    for (int r = 0; r < 4; ++r) {
      int m = hrow + rg*16 + lhi*4 + r;
      float sum = rs_[m][0] + rs_[m][1];
      float sq  = rq_[m][0] + rq_[m][1];
      float mu  = sum * (1.f/(float)D_);
      float var = sq * (1.f/(float)D_) - mu*mu;
      mu_r[r]   = mu;
      rstd_r[r] = rsqrtf(var + 1e-5f);
    }
    #pragma unroll
    for (int tile = 0; tile < 16; ++tile) {
      int n = cs*256 + tile*16 + llo;
      float g = gamma[n], bt = beta[n];
      #pragma unroll
      for (int r = 0; r < 4; ++r) {
        int m = hrow + rg*16 + lhi*4 + r;
        out[(size_t)(row0 + m)*D_ + n] = (oacc[tile][r] - mu_r[r]) * rstd_r[r] * g + bt;
      }
    }
  }
}

extern "C" void kernel_launch(void* const* d_in, const int* in_sizes, int n_in,
                              void* d_out, int out_size, void* d_ws, size_t ws_size,
                              hipStream_t stream) {
  const float* x     = (const float*)d_in[0];
  const float* ce    = (const float*)d_in[1];
  const float* Wq    = (const float*)d_in[2];
  const float* bq    = (const float*)d_in[3];
  const float* Wk    = (const float*)d_in[4];
  const float* bk    = (const float*)d_in[5];
  const float* Wv    = (const float*)d_in[6];
  const float* bv    = (const float*)d_in[7];
  const float* Wo    = (const float*)d_in[8];
  const float* bo    = (const float*)d_in[9];
  const float* gamma = (const float*)d_in[10];
  const float* beta  = (const float*)d_in[11];
  float* out = (float*)d_out;

  char* ws = (char*)d_ws;
  float* Kg           = (float*)(ws);                   // 38912
  float* Vg           = (float*)(ws + 40960);           // 38912
  unsigned short* Mtf = (unsigned short*)(ws + 81920);  // 80*512*2 = 81920
  unsigned short* Utf = (unsigned short*)(ws + 163840); // 512*96*2 = 98304
  float* s0g          = (float*)(ws + 262144);          // 320

  prep1<<<(2*C_*D_)/256, 256, 0, stream>>>(ce, Wk, bk, Wv, bv, Kg, Vg);
  prep2<<<CHP_, 512, 0, stream>>>(Wq, bq, Wo, Kg, Vg, Mtf, Utf, s0g);
  fused64<<<NROW/64, 256, 0, stream>>>(x, Mtf, Utf, s0g, bo, gamma, beta, out);
}